// Round 9
// baseline (164.572 us; speedup 1.0000x reference)
//
#include <hip/hip_runtime.h>

#define GAMMA 0.01f
#define B 32
#define G 2048
#define C 16
#define S 8
#define L 3
#define M 16
#define NBLK 256
#define NTHR 512
#define GSTR 16                       // u64 stride for gslot lines (128 B)

// lse in base-2: exp(v/g) = exp2(v * K_EXP); g*log(s) = K_LOG * log2(s)
#define K_EXP 144.26950408889634f     // log2(e) / GAMMA
#define K_LOG 0.006931471805599453f   // GAMMA * ln(2)

#define SCOPE __HIP_MEMORY_SCOPE_AGENT

// Agent-scope relaxed atomics: executed at the L3 coherence point; no
// fences/cache flushes, L2 stays warm for read-only streams (Ipk).
__device__ __forceinline__ void ast(unsigned* p, unsigned v) {
    __hip_atomic_store(p, v, __ATOMIC_RELAXED, SCOPE);
}
__device__ __forceinline__ float aldf(const float* p) {
    return __hip_atomic_load(p, __ATOMIC_RELAXED, SCOPE);
}
__device__ __forceinline__ void astf(float* p, float v) {
    __hip_atomic_store(p, v, __ATOMIC_RELAXED, SCOPE);
}
__device__ __forceinline__ unsigned long long ald64(const unsigned long long* p) {
    return __hip_atomic_load(p, __ATOMIC_RELAXED, SCOPE);
}
__device__ __forceinline__ void ast64(unsigned long long* p, unsigned long long v) {
    __hip_atomic_store(p, v, __ATOMIC_RELAXED, SCOPE);
}

__device__ __forceinline__ float waveMax(float v) {
#pragma unroll
    for (int off = 32; off > 0; off >>= 1)
        v = fmaxf(v, __shfl_xor(v, off, 64));
    return v;
}

__device__ __forceinline__ float red8(const float* s) {
    return fmaxf(fmaxf(fmaxf(s[0], s[1]), fmaxf(s[2], s[3])),
                 fmaxf(fmaxf(s[4], s[5]), fmaxf(s[6], s[7])));
}

// arrive: per-thread vmcnt drain; block max -> one u64 {epoch, blockmax}
// stored to CONTIGUOUS slot[bid]. No waiting.
__device__ __forceinline__ void barArrive(unsigned long long* slot, unsigned ep,
                                          float v, float* scratch) {
    asm volatile("s_waitcnt vmcnt(0) lgkmcnt(0)" ::: "memory");
    float wm = waveMax(v);
    __syncthreads();                  // all threads drained; guards scratch
    if ((threadIdx.x & 63) == 0) scratch[threadIdx.x >> 6] = wm;
    __syncthreads();
    if (threadIdx.x == 0) {
        float bm = red8(scratch);
        ast64(&slot[blockIdx.x], ((unsigned long long)ep << 32) |
                                 (unsigned long long)__float_as_uint(bm));
    }
}

// hierarchical wait (r8's proven 3-hop): 16 leaders relay group-max to padded
// gslot lines; all blocks' wave0 lanes 0-15 poll the 16 gslots.
__device__ __forceinline__ float barWait(const unsigned long long* slot,
                                         unsigned long long* gslot,
                                         unsigned ep, float* scratch) {
    const int t = threadIdx.x;
    if (t < 64) {
        if ((blockIdx.x & 15) == 0) {         // leader relay (block-uniform)
            float pv = -INFINITY;
            if (t < 16) {
                unsigned long long got;
                int guard = 0;
                do { got = ald64(&slot[blockIdx.x + t]); }
                while ((unsigned)(got >> 32) < ep && ++guard < (1 << 17));
                pv = __uint_as_float((unsigned)got);
            }
            float gm = waveMax(pv);
            if (t == 0)
                ast64(&gslot[(size_t)(blockIdx.x >> 4) * GSTR],
                      ((unsigned long long)ep << 32) |
                      (unsigned long long)__float_as_uint(gm));
        }
        float qv = -INFINITY;
        if (t < 16) {
            unsigned long long got;
            int guard = 0;
            do { got = ald64(&gslot[(size_t)t * GSTR]); }
            while ((unsigned)(got >> 32) < ep && ++guard < (1 << 17));
            qv = __uint_as_float((unsigned)got);
        }
        float fm = waveMax(qv);
        if (t == 0) scratch[0] = fm;
    }
    __syncthreads();
    return scratch[0];
}

// flat wait (2-hop): wave0 polls all 256 contiguous slots (4/lane), reduces.
// Used ONLY for the overlapped C-wait, where arrivals happened during the
// preceding ~6us gather phase -> typically succeeds in one round.
__device__ __forceinline__ float flatWaitMax(const unsigned long long* slot,
                                             unsigned ep, float* scratch) {
    const int t = threadIdx.x;
    if (t < 64) {
        unsigned long long g0, g1, g2, g3;
        int guard = 0;
        for (;;) {
            g0 = ald64(&slot[t * 4 + 0]); g1 = ald64(&slot[t * 4 + 1]);
            g2 = ald64(&slot[t * 4 + 2]); g3 = ald64(&slot[t * 4 + 3]);
            bool ready =
                ((unsigned)(g0 >> 32) >= ep) && ((unsigned)(g1 >> 32) >= ep) &&
                ((unsigned)(g2 >> 32) >= ep) && ((unsigned)(g3 >> 32) >= ep);
            if (ready || ++guard >= (1 << 17)) break;
            __builtin_amdgcn_s_sleep(1);
        }
        float pm = fmaxf(
            fmaxf(__uint_as_float((unsigned)g0), __uint_as_float((unsigned)g1)),
            fmaxf(__uint_as_float((unsigned)g2), __uint_as_float((unsigned)g3)));
        pm = waveMax(pm);
        if (t == 0) scratch[0] = pm;
    }
    __syncthreads();
    return scratch[0];
}

// data-only wait for the 7 sibling blocks (same b): slot seen at ep => that
// block's Ry stores are L3-complete (its barArrive drained vmcnt first).
__device__ __forceinline__ void siblingWait(const unsigned long long* slot,
                                            unsigned ep, int b) {
    if (threadIdx.x < 8) {
        unsigned long long got;
        int guard = 0;
        do { got = ald64(&slot[b + 32 * (int)threadIdx.x]); }
        while ((unsigned)(got >> 32) < ep && ++guard < (1 << 17));
    }
    __syncthreads();
}

// Persistent kernel, plain launch: 256 blocks x 512 threads = 1 block/CU,
// 8 waves = 2 waves/SIMD. Block bid -> (b = bid&31, gt = bid>>5).
// Phase A (deferred-scale): sibling-wait -> stage Vrow UNSCALED -> all 192
// gathers/products into body[8][8] regs -> overlapped flat m3-wait -> fold
// s^3 into exp args (y = s3*bm + K_LOG*log2(sum exp2((body-bm)*s3*K_EXP)))
// -> einsum. Phases B/C: t<256 own (b,g); hy/ry in registers.
extern "C" __global__ __launch_bounds__(512, 2) void kmain(
    const float* __restrict__ x, const float* __restrict__ W,
    const int* __restrict__ I,
    unsigned long long* __restrict__ slotA, unsigned long long* __restrict__ slotB,
    unsigned long long* __restrict__ slotC, unsigned long long* __restrict__ gslotA,
    unsigned long long* __restrict__ gslotB, unsigned long long* __restrict__ gslotC,
    unsigned* __restrict__ Ipk, float* __restrict__ Ry, float* __restrict__ out)
{
    __shared__ __align__(16) float Vrow[G];    // 8 KB: UNSCALED V row b
    __shared__ __align__(16) float WsL[C * M]; // transposed softmax(W), [c][m]
    __shared__ float ph[256 * 33];             // 33 KB partial-h combine
    __shared__ float scratch[8];

    const int t = threadIdx.x;
    const int bid = blockIdx.x;
    const int b = bid & 31;
    const int gt = bid >> 5;
    const int ch = t >> 8;                    // c-half (phase A)
    const int gl = t & 255;
    const int g = (gt << 8) + gl;

    // ---- init: per-block Ws (redundant, cheap) + pack I -> byte-offset pairs.
    if (t < 256) {
        const int m = t >> 4, c = t & 15;
        float rmax = -INFINITY;
#pragma unroll
        for (int j = 0; j < C; j++) rmax = fmaxf(rmax, W[m * C + j]);
        float rsum = 0.f;
#pragma unroll
        for (int j = 0; j < C; j++) rsum += __expf(W[m * C + j] - rmax);
        WsL[c * M + m] = __expf(W[m * C + c] - rmax) / rsum;   // [c][m]
    }
    {
        const int tid = bid * NTHR + t;       // items (c,g): blocks 0-63
        if (tid < C * G) {
            const int4* ip4 = (const int4*)(I + (size_t)tid * 24);
            int idx[24];
#pragma unroll
            for (int j = 0; j < 6; j++) {
                int4 v = ip4[j];
                idx[4 * j + 0] = v.x; idx[4 * j + 1] = v.y;
                idx[4 * j + 2] = v.z; idx[4 * j + 3] = v.w;
            }
            unsigned* dst = Ipk + (size_t)tid * 12;
#pragma unroll
            for (int j = 0; j < 12; j++)      // byte offsets (idx*4), packed x2
                ast(&dst[j],
                    ((unsigned)idx[2 * j] << 2) | ((unsigned)idx[2 * j + 1] << 18));
        }
    }
    barArrive(slotC, 1, -INFINITY, scratch);
    (void)barWait(slotC, gslotC, 1, scratch); // full init sync (Ipk visible)

    float ry = 0.f;
    float s = 1.0f;                           // scale of prev R, set per iter
    for (int it = 0; it < 5; it++) {
        // ------- phase A.1: data wait + stage UNSCALED Vrow -------
        if (it == 0) {                        // x visible via dispatch
            const float4* V4 = (const float4*)(x + (size_t)b * G);
            ((float4*)Vrow)[t] = V4[t];       // 512 float4 = full row
        } else {
            siblingWait(slotC, it + 1, b);    // only the 8 producers of row b
            const float* src = Ry + (size_t)b * G;
#pragma unroll
            for (int j = 0; j < 4; j++) {
                const int gg = t + j * 512;
                Vrow[gg] = aldf(&src[gg]);    // UNSCALED (s folded later)
            }
        }
        __syncthreads();

        // ------- phase A.2: 192 gathers + products (scale-independent) -------
        float bodyv[8][8];                    // fully unrolled -> registers
        float bmv[8];
        const char* vb = (const char*)Vrow;
#pragma unroll
        for (int cc = 0; cc < 8; cc++) {
            const int c = ch * 8 + cc;
            const uint4* ip = (const uint4*)(Ipk + ((size_t)c * G + g) * 12);
            uint4 u0 = ip[0], u1 = ip[1], u2 = ip[2];
            unsigned w[12] = {u0.x, u0.y, u0.z, u0.w, u1.x, u1.y,
                              u1.z, u1.w, u2.x, u2.y, u2.z, u2.w};
            float vv[24];
#pragma unroll
            for (int q = 0; q < 12; q++) {    // 24 random LDS b32 gathers
                vv[2 * q]     = *(const float*)(vb + (w[q] & 0xffffu));
                vv[2 * q + 1] = *(const float*)(vb + (w[q] >> 16));
            }
#pragma unroll
            for (int ss = 0; ss < S; ss++)
                bodyv[cc][ss] = vv[ss * 3] * vv[ss * 3 + 1] * vv[ss * 3 + 2];
            float bm = bodyv[cc][0];
#pragma unroll
            for (int ss = 1; ss < S; ss++) bm = fmaxf(bm, bodyv[cc][ss]);
            bmv[cc] = bm;
        }
        __builtin_amdgcn_sched_barrier(0);    // keep gathers above the wait

        // ------- phase A.3: overlapped m3 wait (arrivals long done) -------
        if (it > 0) {
            float m3v = flatWaitMax(slotC, it + 1, scratch);
            s = (m3v > 1.0f) ? 1.0f / m3v : 1.0f;
        } else {
            s = 1.0f;
        }
        const float s3 = s * s * s;
        const float ke = s3 * K_EXP;

        // ------- phase A.4: fold scale, lse_S, fused einsum -------
        float h[M];
#pragma unroll
        for (int m = 0; m < M; m++) h[m] = 0.f;
        float ymax = -INFINITY;
#pragma unroll
        for (int cc = 0; cc < 8; cc++) {
            const int c = ch * 8 + cc;
            const float bm = bmv[cc];
            float sum = 0.f;
#pragma unroll
            for (int ss = 0; ss < S; ss++)
                sum += exp2f((bodyv[cc][ss] - bm) * ke);
            float y = fmaf(K_LOG, log2f(sum), s3 * bm);   // scaled Cv
            ymax = fmaxf(ymax, y);
            const float4* Wc = (const float4*)&WsL[c * M];
            float4 w0 = Wc[0], w1 = Wc[1], w2 = Wc[2], w3 = Wc[3];
            const float wv[16] = {w0.x, w0.y, w0.z, w0.w, w1.x, w1.y, w1.z, w1.w,
                                  w2.x, w2.y, w2.z, w2.w, w3.x, w3.y, w3.z, w3.w};
#pragma unroll
            for (int m = 0; m < M; m++)       // s1 deferred (linear)
                h[m] = fmaf(wv[m], y, h[m]);
        }
        // partial h -> LDS; stride 33 -> 2-way bank aliasing = free
#pragma unroll
        for (int m = 0; m < M; m++)
            ph[gl * 33 + ch * 16 + m] = h[m];
        barArrive(slotA, it + 1, ymax, scratch);
        // overlap: m1-independent combine (ph covered by arrive's syncs)
        float hraw[M];
        if (t < 256) {
#pragma unroll
            for (int m = 0; m < M; m++)
                hraw[m] = ph[t * 33 + m] + ph[t * 33 + 16 + m];
        }
        float m1 = barWait(slotA, gslotA, it + 1, scratch);

        // ---------------- phase B: s1-scale + lse_M (registers) ----------
        float hy = -INFINITY;
        if (t < 256) {
            float s1 = (m1 > 1.0f) ? 1.0f / m1 : 1.0f;
            float hv[M];
            float hm = -INFINITY;
#pragma unroll
            for (int m = 0; m < M; m++) {
                hv[m] = s1 * hraw[m];
                hm = fmaxf(hm, hv[m]);
            }
            float sum = 0.f;
#pragma unroll
            for (int m = 0; m < M; m++) sum += exp2f((hv[m] - hm) * K_EXP);
            hy = fmaf(K_LOG, log2f(sum), hm);
        }
        barArrive(slotB, it + 1, hy, scratch);
        // m2-independent: Rv = s * Rprev (Vrow is UNSCALED now)
        float Rv = (t < 256) ? s * Vrow[(gt << 8) + t] : 0.f;
        float m2 = barWait(slotB, gslotB, it + 1, scratch);

        // ---------------- phase C: lse_2 -> Ry ------------------
        float rt = -INFINITY;
        if (t < 256) {
            float s2 = (m2 > 1.0f) ? 1.0f / m2 : 1.0f;
            float rv = s2 * hy;
            float a = fmaxf(Rv, rv), d = fminf(Rv, rv);
            ry = fmaf(K_LOG, log2f(1.0f + exp2f((d - a) * K_EXP)), a);
            astf(&Ry[(size_t)b * G + (gt << 8) + t], ry);  // next A reads row b
            rt = ry;
        }
        barArrive(slotC, it + 2, rt, scratch);
        // in-loop C wait happens inside next iteration's phase A (overlapped)
    }

    // ---------------- output (ry in register; final full C wait) ----------
    float m3 = barWait(slotC, gslotC, 6, scratch);
    if (t < 256) {
        float sf = (m3 > 1.0f) ? 1.0f / m3 : 1.0f;
        out[(size_t)b * G + (gt << 8) + t] = sf * ry;
    }
}

extern "C" void kernel_launch(void* const* d_in, const int* in_sizes, int n_in,
                              void* d_out, int out_size, void* d_ws, size_t ws_size,
                              hipStream_t stream) {
    const float* x = (const float*)d_in[0];   // (B,G)
    const float* W = (const float*)d_in[1];   // (M,C)
    const int*   I = (const int*)d_in[2];     // (C,G,S,L)
    float* out = (float*)d_out;

    // workspace layout (u64 units first)
    unsigned long long* slotA  = (unsigned long long*)d_ws;  // 256 u64 (2 KB)
    unsigned long long* slotB  = slotA + NBLK;               // 2 KB
    unsigned long long* slotC  = slotB + NBLK;               // 2 KB
    unsigned long long* gslotA = slotC + NBLK;               // 16*GSTR u64 (2 KB)
    unsigned long long* gslotB = gslotA + 16 * GSTR;         // 2 KB
    unsigned long long* gslotC = gslotB + 16 * GSTR;         // 2 KB
    float* Ry = (float*)(gslotC + 16 * GSTR);                // B*G
    unsigned* Ipk = (unsigned*)(Ry + (size_t)B * G);         // C*G*12 u32 (1.5MB)

    // Zero barrier state every replay (graph-capturable memset node).
    hipMemsetAsync(slotA, 0, (3 * NBLK + 3 * 16 * GSTR) * sizeof(unsigned long long),
                   stream);

    kmain<<<dim3(NBLK), dim3(NTHR), 0, stream>>>(
        x, W, I, slotA, slotB, slotC, gslotA, gslotB, gslotC, Ipk, Ry, out);
}